// Round 2
// baseline (12728.323 us; speedup 1.0000x reference)
//
#include <hip/hip_runtime.h>
#include <stdint.h>

#define DD 200
#define MM 128
#define JJ 256
#define BB 32
#define TPB 512
#define MEMSTRIDE 201

__device__ inline float sigm(float x) { return 1.f / (1.f + expf(-x)); }

// ---- weight prep: transpose to k-major, pack fp32 pairs along k ----

// Combined gates weight: W2[k][g], k in [0,400): k<200 -> w_ih[g][k], k>=200 -> w_hh[g][k-200]
// Wg2[k2*800+g] = float2(W2[2k2][g], W2[2k2+1][g])
__global__ void pack_gates_w(const float* __restrict__ w_ih, const float* __restrict__ w_hh,
                             const float* __restrict__ b_ih, const float* __restrict__ b_hh,
                             float2* __restrict__ Wg2, float* __restrict__ bg) {
  int idx = blockIdx.x * blockDim.x + threadIdx.x;
  if (idx < DD * 800) {   // k2 in [0,200), g in [0,800)
    int k2 = idx / 800, g = idx - k2 * 800;
    int k0 = 2 * k2, k1 = k0 + 1;
    float a = (k0 < DD) ? w_ih[g * DD + k0] : w_hh[g * DD + (k0 - DD)];
    float b = (k1 < DD) ? w_ih[g * DD + k1] : w_hh[g * DD + (k1 - DD)];
    Wg2[idx] = make_float2(a, b);
  }
  if (idx < 800) bg[idx] = b_ih[idx] + b_hh[idx];
}

// w_fc1 (200 x 400) -> Tfc1[k2*200+d] = float2(w_fc1[d][2k2], w_fc1[d][2k2+1]), k2<200
__global__ void pack_fc1(const float* __restrict__ w_fc1, float2* __restrict__ Tfc1) {
  int idx = blockIdx.x * blockDim.x + threadIdx.x;
  if (idx < DD * DD) {
    int k2 = idx / DD, d = idx - k2 * DD;
    Tfc1[idx] = make_float2(w_fc1[d * 400 + 2 * k2], w_fc1[d * 400 + 2 * k2 + 1]);
  }
}

// w_fc (200 x 200) -> Tfc[k2*200+d] = float2(w_fc[d][2k2], w_fc[d][2k2+1]), k2<100
__global__ void pack_fc(const float* __restrict__ w_fc, float2* __restrict__ Tfc) {
  int idx = blockIdx.x * blockDim.x + threadIdx.x;
  if (idx < 100 * DD) {
    int k2 = idx / DD, d = idx - k2 * DD;
    Tfc[idx] = make_float2(w_fc[d * DD + 2 * k2], w_fc[d * DD + 2 * k2 + 1]);
  }
}

// ---- main: one block per (b, parity) chain; mem resident in LDS ----
__global__ __launch_bounds__(TPB, 1)
void chain_kernel(const float* __restrict__ cosb, const float* __restrict__ bank,
                  const float* __restrict__ mem_a, const float* __restrict__ mem_b,
                  const float* __restrict__ b_fc, const float* __restrict__ b_fc1,
                  const float2* __restrict__ Wg2, const float2* __restrict__ Tfc1,
                  const float2* __restrict__ Tfc, const float* __restrict__ bg,
                  float* __restrict__ out)
{
  extern __shared__ float mem_s[];               // [128][201] fp32 = 102,912 B
  __shared__ __align__(16) float qh_s[400];      // [0:200]=q, [200:400]=h
  __shared__ __align__(16) float xq_s[400];      // [0:200]=x, [200:400]=q_old
  __shared__ __align__(16) float qsv_s[DD];
  __shared__ __align__(16) float bank_sh[DD];
  __shared__ __align__(16) float gates_s[800];
  __shared__ __align__(16) float logp_s[512];    // 4 partials per row
  __shared__ float cos_s[MM];
  __shared__ float att_s[MM];

  const int t = threadIdx.x;
  const int par = blockIdx.x & 1;
  const int b = blockIdx.x >> 1;

  const float* msrc = (par ? mem_b : mem_a) + b * MM * DD;
  for (int i = t; i < MM * DD; i += TPB) {
    int m = i / DD, d = i - m * DD;
    mem_s[m * MEMSTRIDE + d] = msrc[i];
  }
  __syncthreads();

  float c_reg = 0.f, sv_reg = 0.f;

  for (int j = par; j < JJ; j += 2) {
    const int slot = j >> 1;
    // stage cos_j and bank_j (disjoint arrays/threads vs prev-step mem write)
    if (t < MM) cos_s[t] = cosb[(b * JJ + j) * MM + t];
    else if (t >= 256 && t < 256 + DD) bank_sh[t - 256] = bank[(j * BB + b) * DD + (t - 256)];
    __syncthreads();

    // h0 = cos_j . mem ; q0 = fc(bank_j)
    if (t < DD) {
      float ha = 0.f, hb = 0.f;
      #pragma unroll 4
      for (int m = 0; m < MM; m += 2) {
        ha = fmaf(cos_s[m], mem_s[m * MEMSTRIDE + t], ha);
        hb = fmaf(cos_s[m + 1], mem_s[(m + 1) * MEMSTRIDE + t], hb);
      }
      float qa = b_fc[t], qb = 0.f;
      const float2* wp = Tfc + t;
      const float2* bv = reinterpret_cast<const float2*>(bank_sh);
      #pragma unroll 2
      for (int k2 = 0; k2 < 100; k2 += 2) {
        float2 w0 = wp[k2 * DD], w1 = wp[(k2 + 1) * DD];
        float2 v0 = bv[k2], v1 = bv[k2 + 1];
        qa = fmaf(w0.x, v0.x, qa); qa = fmaf(w0.y, v0.y, qa);
        qb = fmaf(w1.x, v1.x, qb); qb = fmaf(w1.y, v1.y, qb);
      }
      qh_s[200 + t] = ha + hb;
      float q = qa + qb;
      qh_s[t] = q;
      xq_s[200 + t] = q;
      c_reg = 0.f;
    }
    __syncthreads();

    for (int p = 0; p < 3; ++p) {
      // gates[g] = [q,h] @ W2[:,g] + bg[g]; threads t<400 do outputs t and t+400
      if (t < 400) {
        const float2* qv = reinterpret_cast<const float2*>(qh_s);
        const float2* w0p = Wg2 + t;
        const float2* w1p = Wg2 + t + 400;
        float a0 = bg[t], a1 = bg[t + 400], c0 = 0.f, c1 = 0.f;
        #pragma unroll 2
        for (int k2 = 0; k2 < 200; k2 += 2) {
          float2 v0 = qv[k2], v1 = qv[k2 + 1];
          float2 x0 = w0p[k2 * 800], y0 = w1p[k2 * 800];
          float2 x1 = w0p[(k2 + 1) * 800], y1 = w1p[(k2 + 1) * 800];
          a0 = fmaf(x0.x, v0.x, a0); a0 = fmaf(x0.y, v0.y, a0);
          a1 = fmaf(y0.x, v0.x, a1); a1 = fmaf(y0.y, v0.y, a1);
          c0 = fmaf(x1.x, v1.x, c0); c0 = fmaf(x1.y, v1.y, c0);
          c1 = fmaf(y1.x, v1.x, c1); c1 = fmaf(y1.y, v1.y, c1);
        }
        gates_s[t] = a0 + c0;
        gates_s[t + 400] = a1 + c1;
      }
      __syncthreads();

      // LSTM cell update
      if (t < DD) {
        float ig = gates_s[t], fg = gates_s[200 + t], gg = gates_s[400 + t], og = gates_s[600 + t];
        c_reg = sigm(fg) * c_reg + sigm(ig) * tanhf(gg);
        float h = sigm(og) * tanhf(c_reg);
        qh_s[200 + t] = h;
        xq_s[200 + t] = qh_s[t];   // stash current q for the concat
      }
      __syncthreads();

      // logits[m] = h . mem[m,:], split 4-way over d across all 512 threads
      {
        int m = t >> 2, qd = t & 3;
        const float* mrow = mem_s + m * MEMSTRIDE;
        const float* hv = qh_s + 200;
        float l0 = 0.f, l1 = 0.f;
        int d0 = qd * 50;
        #pragma unroll 5
        for (int d = d0; d < d0 + 50; d += 2) {
          l0 = fmaf(hv[d], mrow[d], l0);
          l1 = fmaf(hv[d + 1], mrow[d + 1], l1);
        }
        logp_s[t] = l0 + l1;
      }
      __syncthreads();

      // softmax over 128 rows, wave 0 only
      if (t < 64) {
        float4 pa = *reinterpret_cast<const float4*>(&logp_s[4 * t]);
        float4 pb = *reinterpret_cast<const float4*>(&logp_s[4 * (t + 64)]);
        float l0 = (pa.x + pa.y) + (pa.z + pa.w);
        float l1 = (pb.x + pb.y) + (pb.z + pb.w);
        float mx = fmaxf(l0, l1);
        #pragma unroll
        for (int o = 1; o < 64; o <<= 1) mx = fmaxf(mx, __shfl_xor(mx, o));
        float e0 = expf(l0 - mx), e1 = expf(l1 - mx);
        float s = e0 + e1;
        #pragma unroll
        for (int o = 1; o < 64; o <<= 1) s += __shfl_xor(s, o);
        float inv = 1.f / s;
        att_s[t] = e0 * inv;
        att_s[t + 64] = e1 * inv;
      }
      __syncthreads();

      // x = att @ mem
      if (t < DD) {
        float xa = 0.f, xb = 0.f;
        #pragma unroll 4
        for (int m = 0; m < MM; m += 2) {
          xa = fmaf(att_s[m], mem_s[m * MEMSTRIDE + t], xa);
          xb = fmaf(att_s[m + 1], mem_s[(m + 1) * MEMSTRIDE + t], xb);
        }
        xq_s[t] = xa + xb;
      }
      __syncthreads();

      // q = [x, q_old] @ w_fc1.T + b_fc1
      if (t < DD) {
        float aa = b_fc1[t], ab = 0.f;
        const float2* wp = Tfc1 + t;
        const float2* xv = reinterpret_cast<const float2*>(xq_s);
        #pragma unroll 2
        for (int k2 = 0; k2 < 200; k2 += 2) {
          float2 w0 = wp[k2 * DD], w1 = wp[(k2 + 1) * DD];
          float2 v0 = xv[k2], v1 = xv[k2 + 1];
          aa = fmaf(w0.x, v0.x, aa); aa = fmaf(w0.y, v0.y, aa);
          ab = fmaf(w1.x, v1.x, ab); ab = fmaf(w1.y, v1.y, ab);
        }
        qh_s[t] = aa + ab;   // safe: this phase reads only xq_s
      }
      __syncthreads();
    }

    // emit q, prepare q + slot_vec
    if (t < DD) {
      float q = qh_s[t];
      out[(b * JJ + j) * DD + t] = q;
      sv_reg = mem_s[slot * MEMSTRIDE + t];
      qsv_s[t] = q + sv_reg;
    }
    __syncthreads();

    // z = tanh((q+sv) @ w_fc.T + 2*b_fc); mem[slot] = z * sv
    if (t < DD) {
      float aa = 2.f * b_fc[t], ab = 0.f;
      const float2* wp = Tfc + t;
      const float2* qv = reinterpret_cast<const float2*>(qsv_s);
      #pragma unroll 2
      for (int k2 = 0; k2 < 100; k2 += 2) {
        float2 w0 = wp[k2 * DD], w1 = wp[(k2 + 1) * DD];
        float2 v0 = qv[k2], v1 = qv[k2 + 1];
        aa = fmaf(w0.x, v0.x, aa); aa = fmaf(w0.y, v0.y, aa);
        ab = fmaf(w1.x, v1.x, ab); ab = fmaf(w1.y, v1.y, ab);
      }
      float z = tanhf(aa + ab);
      mem_s[slot * MEMSTRIDE + t] = z * sv_reg;
    }
    // no end barrier needed: next iteration's post-stage barrier orders the mem
    // write before the next h0 read; staging threads don't touch mem_s.
  }
}

extern "C" void kernel_launch(void* const* d_in, const int* in_sizes, int n_in,
                              void* d_out, int out_size, void* d_ws, size_t ws_size,
                              hipStream_t stream) {
  const float* cosb  = (const float*)d_in[0];
  const float* bank  = (const float*)d_in[1];
  const float* mem_a = (const float*)d_in[2];
  const float* mem_b = (const float*)d_in[3];
  const float* w_fc  = (const float*)d_in[4];
  const float* b_fc  = (const float*)d_in[5];
  const float* w_fc1 = (const float*)d_in[6];
  const float* b_fc1 = (const float*)d_in[7];
  const float* w_ih  = (const float*)d_in[8];
  const float* w_hh  = (const float*)d_in[9];
  const float* b_ih  = (const float*)d_in[10];
  const float* b_hh  = (const float*)d_in[11];

  char* ws = (char*)d_ws;
  float2* Wg2  = (float2*)(ws);              // 200*800*8 = 1,280,000 B
  float2* Tfc1 = (float2*)(ws + 1280000);    // 200*200*8 =   320,000 B
  float2* Tfc  = (float2*)(ws + 1600000);    // 100*200*8 =   160,000 B
  float*  bg   = (float*) (ws + 1760000);    // 800*4     =     3,200 B

  pack_gates_w<<<(DD * 800 + 255) / 256, 256, 0, stream>>>(w_ih, w_hh, b_ih, b_hh, Wg2, bg);
  pack_fc1<<<(DD * DD + 255) / 256, 256, 0, stream>>>(w_fc1, Tfc1);
  pack_fc<<<(100 * DD + 255) / 256, 256, 0, stream>>>(w_fc, Tfc);

  int dynbytes = MM * MEMSTRIDE * sizeof(float);  // 102,912 B
  hipFuncSetAttribute(reinterpret_cast<const void*>(chain_kernel),
                      hipFuncAttributeMaxDynamicSharedMemorySize, dynbytes);
  chain_kernel<<<64, TPB, dynbytes, stream>>>(cosb, bank, mem_a, mem_b, b_fc, b_fc1,
                                              Wg2, Tfc1, Tfc, bg, (float*)d_out);
}

// Round 3
// 7091.324 us; speedup vs baseline: 1.7949x; 1.7949x over previous
//
#include <hip/hip_runtime.h>
#include <stdint.h>

#define DD 200
#define MM 128
#define JJ 256
#define BB 32
#define TPB 1024
#define MEMSTRIDE 201

__device__ inline float sigm(float x) { return 1.f / (1.f + expf(-x)); }

// ---- weight prep: transpose to k-major, pack fp32 QUADS along k ----

// W2[k][g], k in [0,400): k<200 -> w_ih[g][k], k>=200 -> w_hh[g][k-200]
// Wg4[k4*800+g] = float4(W2[4k4][g], .., W2[4k4+3][g]), k4 in [0,100)
__global__ void pack_gates_w(const float* __restrict__ w_ih, const float* __restrict__ w_hh,
                             const float* __restrict__ b_ih, const float* __restrict__ b_hh,
                             float4* __restrict__ Wg4, float* __restrict__ bg) {
  int idx = blockIdx.x * blockDim.x + threadIdx.x;
  if (idx < 100 * 800) {
    int k4 = idx / 800, g = idx - k4 * 800;
    float v[4];
    #pragma unroll
    for (int e = 0; e < 4; ++e) {
      int k = 4 * k4 + e;
      v[e] = (k < DD) ? w_ih[g * DD + k] : w_hh[g * DD + (k - DD)];
    }
    Wg4[idx] = make_float4(v[0], v[1], v[2], v[3]);
  }
  if (idx < 800) bg[idx] = b_ih[idx] + b_hh[idx];
}

// w_fc1 (200 x 400) -> Tfc14[k4*200+d] = w_fc1[d][4k4..4k4+3], k4 in [0,100)
__global__ void pack_fc1(const float* __restrict__ w_fc1, float4* __restrict__ Tfc14) {
  int idx = blockIdx.x * blockDim.x + threadIdx.x;
  if (idx < 100 * DD) {
    int k4 = idx / DD, d = idx - k4 * DD;
    const float* p = w_fc1 + d * 400 + 4 * k4;
    Tfc14[idx] = make_float4(p[0], p[1], p[2], p[3]);
  }
}

// w_fc (200 x 200) -> Tfc4[k4*200+d] = w_fc[d][4k4..4k4+3], k4 in [0,50)
__global__ void pack_fc(const float* __restrict__ w_fc, float4* __restrict__ Tfc4) {
  int idx = blockIdx.x * blockDim.x + threadIdx.x;
  if (idx < 50 * DD) {
    int k4 = idx / DD, d = idx - k4 * DD;
    const float* p = w_fc + d * DD + 4 * k4;
    Tfc4[idx] = make_float4(p[0], p[1], p[2], p[3]);
  }
}

// ---- main: one block per (b, parity) chain; mem resident in LDS ----
__global__ __launch_bounds__(TPB, 4)
void chain_kernel(const float* __restrict__ cosb, const float* __restrict__ bank,
                  const float* __restrict__ mem_a, const float* __restrict__ mem_b,
                  const float* __restrict__ b_fc, const float* __restrict__ b_fc1,
                  const float4* __restrict__ Wg4, const float4* __restrict__ Tfc14,
                  const float4* __restrict__ Tfc4, const float* __restrict__ bg,
                  float* __restrict__ out)
{
  extern __shared__ float mem_s[];               // [128][201] = 102,912 B
  __shared__ __align__(16) float qh_s[400];      // [0:200)=q, [200:400)=h
  __shared__ __align__(16) float xq_s[400];      // [200:400)=q_old (concat tail)
  __shared__ __align__(16) float qsv_s[DD];
  __shared__ __align__(16) float bank_sh[2][DD];
  __shared__ __align__(16) float q0_s[2][DD];
  __shared__ __align__(16) float cos_s[2][MM];
  __shared__ __align__(16) float gates_s[800];
  __shared__ __align__(16) float logp_s[1024];
  __shared__ __align__(16) float hp_s[400];
  __shared__ __align__(16) float xp_s[400];
  __shared__ __align__(16) float fq_s[400];
  __shared__ __align__(16) float att_s[MM];

  const int t = threadIdx.x;
  const int par = blockIdx.x & 1;
  const int b = blockIdx.x >> 1;

  // load mem + stage step-0 cos/bank
  const float* msrc = (par ? mem_b : mem_a) + b * MM * DD;
  for (int i = t; i < MM * DD; i += TPB) {
    int m = i / DD, d = i - m * DD;
    mem_s[m * MEMSTRIDE + d] = msrc[i];
  }
  if (t < MM) cos_s[0][t] = cosb[(b * JJ + par) * MM + t];
  else if (t < MM + DD) bank_sh[0][t - MM] = bank[(par * BB + b) * DD + (t - MM)];
  __syncthreads();

  // q0 for step 0 (prologue only)
  if (t < DD) {
    float a0 = b_fc[t], a1 = 0.f, a2 = 0.f, a3 = 0.f;
    const float4* bv = reinterpret_cast<const float4*>(bank_sh[0]);
    const float4* wp = Tfc4 + t;
    #pragma unroll 5
    for (int k4 = 0; k4 < 50; ++k4) {
      float4 w = wp[k4 * DD], v = bv[k4];
      a0 = fmaf(w.x, v.x, a0); a1 = fmaf(w.y, v.y, a1);
      a2 = fmaf(w.z, v.z, a2); a3 = fmaf(w.w, v.w, a3);
    }
    q0_s[0][t] = (a0 + a1) + (a2 + a3);
  }
  __syncthreads();

  float c_reg = 0.f, sv_reg = 0.f;

  for (int s = 0; s < JJ / 2; ++s) {
    const int j = 2 * s + par;
    const int cur = s & 1, nxt = cur ^ 1;

    // Phase A: h0 partials (2-way m-split) | stage next cos/bank
    if (t < 400) {
      int half = (t >= DD) ? 1 : 0;
      int d = t - half * DD;
      const float* cs = cos_s[cur] + half * 64;
      const float* mp = mem_s + (half * 64) * MEMSTRIDE + d;
      float a0 = 0.f, a1 = 0.f;
      #pragma unroll 4
      for (int m = 0; m < 64; m += 2) {
        a0 = fmaf(cs[m], mp[m * MEMSTRIDE], a0);
        a1 = fmaf(cs[m + 1], mp[(m + 1) * MEMSTRIDE], a1);
      }
      hp_s[half * DD + d] = a0 + a1;
    } else if (t < 400 + MM + DD) {
      if (s + 1 < JJ / 2) {
        int u = t - 400, j2 = j + 2;
        if (u < MM) cos_s[nxt][u] = cosb[(b * JJ + j2) * MM + u];
        else bank_sh[nxt][u - MM] = bank[(j2 * BB + b) * DD + (u - MM)];
      }
    }
    __syncthreads();

    // Phase B: reduce h partials, install q0
    if (t < DD) {
      float h = hp_s[t] + hp_s[DD + t];
      float q = q0_s[cur][t];
      qh_s[200 + t] = h;
      qh_s[t] = q;
      xq_s[200 + t] = q;
      c_reg = 0.f;
    }
    __syncthreads();

    for (int p = 0; p < 3; ++p) {
      // Phase C: gates GEMV (t<800) | next-step q0 (waves 13-15, p==0)
      if (t < 800) {
        const float4* qv4 = reinterpret_cast<const float4*>(qh_s);
        const float4* wp = Wg4 + t;
        float a0 = bg[t], a1 = 0.f, a2 = 0.f, a3 = 0.f;
        for (int k4 = 0; k4 < 100; k4 += 4) {
          float4 w0 = wp[k4 * 800], w1 = wp[(k4 + 1) * 800];
          float4 w2 = wp[(k4 + 2) * 800], w3 = wp[(k4 + 3) * 800];
          float4 v0 = qv4[k4], v1 = qv4[k4 + 1], v2 = qv4[k4 + 2], v3 = qv4[k4 + 3];
          a0 = fmaf(w0.x, v0.x, a0); a0 = fmaf(w0.y, v0.y, a0);
          a0 = fmaf(w0.z, v0.z, a0); a0 = fmaf(w0.w, v0.w, a0);
          a1 = fmaf(w1.x, v1.x, a1); a1 = fmaf(w1.y, v1.y, a1);
          a1 = fmaf(w1.z, v1.z, a1); a1 = fmaf(w1.w, v1.w, a1);
          a2 = fmaf(w2.x, v2.x, a2); a2 = fmaf(w2.y, v2.y, a2);
          a2 = fmaf(w2.z, v2.z, a2); a2 = fmaf(w2.w, v2.w, a2);
          a3 = fmaf(w3.x, v3.x, a3); a3 = fmaf(w3.y, v3.y, a3);
          a3 = fmaf(w3.z, v3.z, a3); a3 = fmaf(w3.w, v3.w, a3);
        }
        gates_s[t] = (a0 + a1) + (a2 + a3);
      } else if (p == 0 && t >= 832 && s + 1 < JJ / 2) {
        int u = t - 832;   // 192 wave-aligned threads; u<8 take a second d
        for (int d = u; d < DD; d += 192) {
          float a0 = b_fc[d], a1 = 0.f, a2 = 0.f, a3 = 0.f;
          const float4* bv = reinterpret_cast<const float4*>(bank_sh[nxt]);
          const float4* wp = Tfc4 + d;
          #pragma unroll 5
          for (int k4 = 0; k4 < 50; ++k4) {
            float4 w = wp[k4 * DD], v = bv[k4];
            a0 = fmaf(w.x, v.x, a0); a1 = fmaf(w.y, v.y, a1);
            a2 = fmaf(w.z, v.z, a2); a3 = fmaf(w.w, v.w, a3);
          }
          q0_s[nxt][d] = (a0 + a1) + (a2 + a3);
        }
      }
      __syncthreads();

      // Phase D: LSTM cell
      if (t < DD) {
        float ig = gates_s[t], fg = gates_s[200 + t], gg = gates_s[400 + t], og = gates_s[600 + t];
        c_reg = sigm(fg) * c_reg + sigm(ig) * tanhf(gg);
        float h = sigm(og) * tanhf(c_reg);
        qh_s[200 + t] = h;
        xq_s[200 + t] = qh_s[t];   // stash current q for the concat
      }
      __syncthreads();

      // Phase E: logits, 8-way d-split, wave-uniform qd
      {
        int qd = t >> 7, m = t & 127;
        const float* hv = qh_s + 200 + qd * 25;
        const float* mrow = mem_s + m * MEMSTRIDE + qd * 25;
        float l0 = 0.f, l1 = 0.f;
        #pragma unroll
        for (int d = 0; d < 24; d += 2) {
          l0 = fmaf(hv[d], mrow[d], l0);
          l1 = fmaf(hv[d + 1], mrow[d + 1], l1);
        }
        l0 = fmaf(hv[24], mrow[24], l0);
        logp_s[qd * 128 + m] = l0 + l1;
      }
      __syncthreads();

      // Phase F: softmax over 128, wave 0
      if (t < 64) {
        float l0 = 0.f, l1 = 0.f;
        #pragma unroll
        for (int qd = 0; qd < 8; ++qd) {
          l0 += logp_s[qd * 128 + t];
          l1 += logp_s[qd * 128 + t + 64];
        }
        float mx = fmaxf(l0, l1);
        #pragma unroll
        for (int o = 1; o < 64; o <<= 1) mx = fmaxf(mx, __shfl_xor(mx, o));
        float e0 = expf(l0 - mx), e1 = expf(l1 - mx);
        float ssum = e0 + e1;
        #pragma unroll
        for (int o = 1; o < 64; o <<= 1) ssum += __shfl_xor(ssum, o);
        float inv = 1.f / ssum;
        att_s[t] = e0 * inv;
        att_s[t + 64] = e1 * inv;
      }
      __syncthreads();

      // Phase G: x partials (2-way m-split)
      if (t < 400) {
        int half = (t >= DD) ? 1 : 0;
        int d = t - half * DD;
        const float* as = att_s + half * 64;
        const float* mp = mem_s + (half * 64) * MEMSTRIDE + d;
        float a0 = 0.f, a1 = 0.f;
        #pragma unroll 4
        for (int m = 0; m < 64; m += 2) {
          a0 = fmaf(as[m], mp[m * MEMSTRIDE], a0);
          a1 = fmaf(as[m + 1], mp[(m + 1) * MEMSTRIDE], a1);
        }
        xp_s[half * DD + d] = a0 + a1;
      }
      __syncthreads();

      // Phase H: fc1 partials (2-way k-split; kh0 = x-part from partials, kh1 = q_old)
      if (t < 400) {
        int kh = (t >= DD) ? 1 : 0;
        int d = t - kh * DD;
        const float4* wp = Tfc14 + d;
        float a0 = 0.f, a1 = 0.f, a2 = 0.f, a3 = 0.f;
        if (kh == 0) {
          const float4* x0 = reinterpret_cast<const float4*>(xp_s);
          const float4* x1 = reinterpret_cast<const float4*>(xp_s + DD);
          #pragma unroll 5
          for (int k4 = 0; k4 < 50; ++k4) {
            float4 w = wp[k4 * DD];
            float4 va = x0[k4], vb = x1[k4];
            a0 = fmaf(w.x, va.x + vb.x, a0); a1 = fmaf(w.y, va.y + vb.y, a1);
            a2 = fmaf(w.z, va.z + vb.z, a2); a3 = fmaf(w.w, va.w + vb.w, a3);
          }
        } else {
          const float4* qv = reinterpret_cast<const float4*>(xq_s);
          #pragma unroll 5
          for (int k4 = 50; k4 < 100; ++k4) {
            float4 w = wp[k4 * DD], v = qv[k4];
            a0 = fmaf(w.x, v.x, a0); a1 = fmaf(w.y, v.y, a1);
            a2 = fmaf(w.z, v.z, a2); a3 = fmaf(w.w, v.w, a3);
          }
        }
        fq_s[kh * DD + d] = (a0 + a1) + (a2 + a3);
      }
      __syncthreads();

      // Phase I: reduce fc1, emit on last p
      if (t < DD) {
        float qn = fq_s[t] + fq_s[DD + t] + b_fc1[t];
        qh_s[t] = qn;
        if (p == 2) {
          out[(b * JJ + j) * DD + t] = qn;
          sv_reg = mem_s[s * MEMSTRIDE + t];
          qsv_s[t] = qn + sv_reg;
        }
      }
      __syncthreads();
    }

    // Phase K: final fc partials (2-way k-split)
    if (t < 400) {
      int kh = (t >= DD) ? 1 : 0;
      int d = t - kh * DD;
      const float4* wp = Tfc4 + d;
      const float4* qv = reinterpret_cast<const float4*>(qsv_s);
      float a0 = 0.f, a1 = 0.f, a2 = 0.f, a3 = 0.f;
      #pragma unroll 5
      for (int k4 = kh * 25; k4 < kh * 25 + 25; ++k4) {
        float4 w = wp[k4 * DD], v = qv[k4];
        a0 = fmaf(w.x, v.x, a0); a1 = fmaf(w.y, v.y, a1);
        a2 = fmaf(w.z, v.z, a2); a3 = fmaf(w.w, v.w, a3);
      }
      fq_s[kh * DD + d] = (a0 + a1) + (a2 + a3);
    }
    __syncthreads();

    // Phase L: z, mem row update
    if (t < DD) {
      float z = tanhf(fq_s[t] + fq_s[DD + t] + 2.f * b_fc[t]);
      mem_s[s * MEMSTRIDE + t] = z * sv_reg;
    }
    __syncthreads();
  }
}

extern "C" void kernel_launch(void* const* d_in, const int* in_sizes, int n_in,
                              void* d_out, int out_size, void* d_ws, size_t ws_size,
                              hipStream_t stream) {
  const float* cosb  = (const float*)d_in[0];
  const float* bank  = (const float*)d_in[1];
  const float* mem_a = (const float*)d_in[2];
  const float* mem_b = (const float*)d_in[3];
  const float* w_fc  = (const float*)d_in[4];
  const float* b_fc  = (const float*)d_in[5];
  const float* w_fc1 = (const float*)d_in[6];
  const float* b_fc1 = (const float*)d_in[7];
  const float* w_ih  = (const float*)d_in[8];
  const float* w_hh  = (const float*)d_in[9];
  const float* b_ih  = (const float*)d_in[10];
  const float* b_hh  = (const float*)d_in[11];

  char* ws = (char*)d_ws;
  float4* Wg4   = (float4*)(ws);              // 100*800*16 = 1,280,000 B
  float4* Tfc14 = (float4*)(ws + 1280000);    // 100*200*16 =   320,000 B
  float4* Tfc4  = (float4*)(ws + 1600000);    //  50*200*16 =   160,000 B
  float*  bg    = (float*) (ws + 1760000);    // 800*4      =     3,200 B

  pack_gates_w<<<(100 * 800 + 255) / 256, 256, 0, stream>>>(w_ih, w_hh, b_ih, b_hh, Wg4, bg);
  pack_fc1<<<(100 * DD + 255) / 256, 256, 0, stream>>>(w_fc1, Tfc14);
  pack_fc<<<(50 * DD + 255) / 256, 256, 0, stream>>>(w_fc, Tfc4);

  int dynbytes = MM * MEMSTRIDE * sizeof(float);  // 102,912 B
  hipFuncSetAttribute(reinterpret_cast<const void*>(chain_kernel),
                      hipFuncAttributeMaxDynamicSharedMemorySize, dynbytes);
  chain_kernel<<<64, TPB, dynbytes, stream>>>(cosb, bank, mem_a, mem_b, b_fc, b_fc1,
                                              Wg4, Tfc14, Tfc4, bg, (float*)d_out);
}